// Round 13
// baseline (231.454 us; speedup 1.0000x reference)
//
#include <hip/hip_runtime.h>
#include <stdint.h>

// Match numpy op-for-op rounding: no FMA contraction anywhere.
#pragma clang fp contract(off)

#define BATCH 8
#define HH 64
#define WW 64
#define KA 9
#define NBOX (HH * WW * KA)   // 36864 per batch
#define TOPN 2000
#define NPAD 2048
#define NW 32                 // 64-bit words covering 2048 bits
#define IOU_T 0.7f
#define MINSZ 0.01f
#define EPSF 1e-7f
#define TSTRIDE 33            // LDS tile row stride in u64 (bank-conflict-free)
#define CANDCAP 3072          // candidate buffer (expected ~2300 for uniform)

typedef unsigned int u32;
typedef unsigned long long u64;

__device__ __forceinline__ float clamp01(float x) { return fminf(fmaxf(x, 0.0f), 1.0f); }

// Workgroup barrier with LDS-only drain: does NOT wait vmcnt, so global
// prefetch loads stay in flight across the barrier.
__device__ __forceinline__ void bar_lds()
{
    asm volatile("s_waitcnt lgkmcnt(0)" ::: "memory");
    __builtin_amdgcn_s_barrier();
}

// ---------------------------------------------------------------------------
// Shared box decode (bit-exact same arithmetic everywhere; contract off).
// ---------------------------------------------------------------------------
__device__ __forceinline__ void decode_one(
    const float* __restrict__ scores, const float4* __restrict__ offsets,
    const float* __restrict__ anchors, int gid, int t,
    float4* boxOut, u32* keyOut)
{
    int k = t % KA;
    int pos = t / KA;
    int wx = pos & (WW - 1);
    int hy = pos >> 6;
    float s = scores[gid];
    float4 off = offsets[gid];
    float aw = anchors[2 * k], ah = anchors[2 * k + 1];
    float cx = ((float)wx + 0.5f) * 16.0f;
    float cy = ((float)hy + 0.5f) * 16.0f;
    float pw = (expf(off.z) * aw) / 1024.0f;   // exp(off)*anc/img_wh
    float ph = (expf(off.w) * ah) / 1024.0f;
    float xc = (aw * off.x + cx) / 1024.0f;    // (anc*off + center)/img_wh
    float yc = (ah * off.y + cy) / 1024.0f;
    float x1 = clamp01(xc - pw * 0.5f);
    float y1 = clamp01(yc - ph * 0.5f);
    float x2 = clamp01(xc + pw * 0.5f);
    float y2 = clamp01(yc + ph * 0.5f);
    float sc = clamp01(s);
    float m = ((x2 - x1) > MINSZ && (y2 - y1) > MINSZ) ? 1.0f : 0.0f;
    *boxOut = make_float4(x1 * m, y1 * m, x2 * m, y2 * m);
    *keyOut = __float_as_uint(sc * m);   // score >= 0: bit order == value order
}

// ---------------------------------------------------------------------------
// 0) Zero the global 12-bit histograms (8 x 4096 bins).
// ---------------------------------------------------------------------------
__global__ __launch_bounds__(256) void zero_kernel(uint4* __restrict__ p, int n)
{
    int g = blockIdx.x * 256 + threadIdx.x;
    if (g < n) p[g] = make_uint4(0, 0, 0, 0);
}

// ---------------------------------------------------------------------------
// 1) Decode score keys + global 12-bit histogram (fully parallel).
// ---------------------------------------------------------------------------
__global__ __launch_bounds__(256) void decode_kernel(
    const float* __restrict__ scores, const float4* __restrict__ offsets,
    const float* __restrict__ anchors, u32* __restrict__ keys,
    u32* __restrict__ ghist)
{
    int gid = blockIdx.x * 256 + threadIdx.x;   // grid exactly covers 8*NBOX
    int b = gid / NBOX;
    int t = gid - b * NBOX;
    float4 box; u32 key;
    decode_one(scores, offsets, anchors, gid, t, &box, &key);
    keys[gid] = key;
    atomicAdd(&ghist[(b << 12) + (key >> 20)], 1u);
}

// ---------------------------------------------------------------------------
// Wave-level descending rank-find over a 4096-bin LDS hist: 2 barriers.
// partial[1024] is scratch. Finds bin P (desc cum crosses r) + residual R.
// ---------------------------------------------------------------------------
__device__ __forceinline__ void rank_find_4096(
    const u32* __restrict__ histL, u32* __restrict__ partial,
    int r, u32* Bsh, int* Rsh, int tid)
{
    partial[tid] = histL[4 * tid] + histL[4 * tid + 1]
                 + histL[4 * tid + 2] + histL[4 * tid + 3];
    __syncthreads();
    if (tid < 64) {
        int lane = tid;
        // superseg l (64 bins) total = partial[16l .. 16l+15]
        u32 s = 0;
#pragma unroll
        for (int q = 0; q < 16; ++q) s += partial[lane * 16 + q];
        u32 suf = s;
#pragma unroll
        for (int d = 1; d < 64; d <<= 1) {
            u32 t = __shfl_down(suf, d);
            if (lane + d < 64) suf += t;
        }
        u32 nxt = __shfl_down(suf, 1);
        if (lane == 63) nxt = 0;
        bool cross = (suf >= (u32)r) && (nxt < (u32)r);   // exactly one lane
        u64 bal = __ballot(cross);
        int L = (int)(__ffsll((unsigned long long)bal) - 1);
        u32 above = __shfl(nxt, L);       // count strictly above superseg L
        // bin level within superseg L
        u32 hv = histL[64 * L + lane];
        u32 suf2 = hv;
#pragma unroll
        for (int d = 1; d < 64; d <<= 1) {
            u32 t = __shfl_down(suf2, d);
            if (lane + d < 64) suf2 += t;
        }
        u32 nxt2 = __shfl_down(suf2, 1);
        if (lane == 63) nxt2 = 0;
        u32 mine2 = suf2 + above;
        nxt2 += above;
        if (mine2 >= (u32)r && nxt2 < (u32)r) {
            *Bsh = (u32)(64 * L + lane);
            *Rsh = r - (int)nxt2;
        }
    }
    __syncthreads();
}

// ---------------------------------------------------------------------------
// 2) Per-batch select, ONE global key stream:
//    global hist (from decode) -> P1/r1; uint4 stream splits definite -> sel
//    and candidates -> cand; 3x12-bit LDS radix over cand -> exact T48;
//    append exactly r1; bitonic sort 2048 desc; re-decode top-2000 boxes.
// ---------------------------------------------------------------------------
__global__ __launch_bounds__(1024) void select_kernel(
    const u32* __restrict__ keys, const u32* __restrict__ ghist,
    const float* __restrict__ scores, const float4* __restrict__ offsets,
    const float* __restrict__ anchors, float4* __restrict__ topBoxes)
{
    int b = blockIdx.x;
    int tid = threadIdx.x;
    int lane = tid & 63;
    const u32* kb = keys + (size_t)b * NBOX;

    __shared__ u32 hist[4096];    // 16 KB
    __shared__ u32 partial[1024]; //  4 KB
    __shared__ u64 sel[NPAD];     // 16 KB
    __shared__ u64 cand[CANDCAP]; // 24 KB  (total ~60.5 KB)
    __shared__ u32 Bsh;
    __shared__ int Rsh;
    __shared__ int ctr, cctr;

    // ---- load global hist; find P1/r1 ----
    if (tid == 0) { ctr = 0; cctr = 0; }
    for (int i = tid; i < 4096; i += 1024) hist[i] = ghist[(b << 12) + i];
    for (int i = tid; i < NPAD; i += 1024) sel[i] = 0ull;
    __syncthreads();
    rank_find_4096(hist, partial, TOPN, &Bsh, &Rsh, tid);
    u32 P1 = Bsh;
    int r1 = Rsh;          // need top-r1 of the candidates (top12 == P1)
    __syncthreads();

    // ---- single uint4 stream: definite -> sel, candidates -> cand ----
    const uint4* kb4 = (const uint4*)kb;
#pragma unroll 1
    for (int it = 0; it < NBOX / 4096; ++it) {
        int i4 = it * 1024 + tid;           // uint4 index
        uint4 kv = kb4[i4];
        u32 karr[4] = { kv.x, kv.y, kv.z, kv.w };
        u64 bd[4], bc[4];
        int totd = 0, totc = 0;
#pragma unroll
        for (int q = 0; q < 4; ++q) {
            u32 top = karr[q] >> 20;
            bd[q] = __ballot(top > P1);
            bc[q] = __ballot(top == P1);
            totd += (int)__popcll(bd[q]);
            totc += (int)__popcll(bc[q]);
        }
        int based = 0, basec = 0;
        if (lane == 0) {
            if (totd) based = atomicAdd(&ctr, totd);
            if (totc) basec = atomicAdd(&cctr, totc);
        }
        based = __shfl(based, 0);
        basec = __shfl(basec, 0);
        u64 lmask = (1ull << lane) - 1ull;
        int offd = 0, offc = 0;
#pragma unroll
        for (int q = 0; q < 4; ++q) {
            u32 key = karr[q];
            int i = i4 * 4 + q;
            u64 K = ((u64)key << 16) | (u64)(0xFFFFu - (u32)i);
            u32 top = key >> 20;
            if (top > P1) {
                int slot = based + offd + (int)__popcll(bd[q] & lmask);
                if (slot < NPAD) sel[slot] = K;
            } else if (top == P1) {
                int cslot = basec + offc + (int)__popcll(bc[q] & lmask);
                if (cslot < CANDCAP) cand[cslot] = K;
            }
            offd += (int)__popcll(bd[q]);
            offc += (int)__popcll(bc[q]);
        }
    }
    __syncthreads();
    int cc = cctr < CANDCAP ? cctr : CANDCAP;

    // ---- 3x12-bit LDS radix over candidates: exact T48 ----
    u64 prefix = (u64)P1;               // == K>>36 for every candidate
    int r = r1;
    for (int p = 0; p < 3; ++p) {
        int shift = 24 - 12 * p;
        for (int i = tid; i < 4096; i += 1024) hist[i] = 0;
        __syncthreads();
        for (int c = tid; c < cc; c += 1024) {
            u64 K = cand[c];
            if ((K >> (shift + 12)) == prefix)
                atomicAdd(&hist[(u32)((K >> shift) & 0xFFFull)], 1u);
        }
        __syncthreads();
        rank_find_4096(hist, partial, r, &Bsh, &Rsh, tid);
        prefix = (prefix << 12) | (u64)Bsh;
        r = Rsh;
        __syncthreads();
    }
    u64 T48 = prefix;   // exact r1-th largest candidate key (unique keys)

    // append exactly r1 candidates >= T48
    for (int c = tid; c < cc; c += 1024) {
        u64 K = cand[c];
        bool take = (K >= T48);
        u64 bal = __ballot(take);
        int base = 0;
        if (lane == 0 && bal) base = atomicAdd(&ctr, (int)__popcll(bal));
        base = __shfl(base, 0);
        if (take) {
            int slot = base + (int)__popcll(bal & ((1ull << lane) - 1ull));
            if (slot < NPAD) sel[slot] = K;
        }
    }
    __syncthreads();

    // ---- bitonic sort 2048 desc ----
    for (int k = 2; k <= NPAD; k <<= 1) {
        for (int j = k >> 1; j > 0; j >>= 1) {
#pragma unroll
            for (int n = 0; n < 2; ++n) {
                int i = tid + n * 1024;
                int ixj = i ^ j;
                if (ixj > i) {
                    bool desc = ((i & k) == 0);
                    u64 a = sel[i], c = sel[ixj];
                    if (desc ? (a < c) : (a > c)) { sel[i] = c; sel[ixj] = a; }
                }
            }
            __syncthreads();
        }
    }

    // re-decode top-2000 boxes; rows 2000..2047 zeroed for safe loads
    for (int i = tid; i < NPAD; i += 1024) {
        float4 v = make_float4(0, 0, 0, 0);
        if (i < TOPN) {
            u64 K = sel[i];
            int idx = 0xFFFF - (int)(K & 0xFFFFull);
            u32 kdummy;
            decode_one(scores, offsets, anchors, b * NBOX + idx, idx, &v, &kdummy);
        }
        topBoxes[b * NPAD + i] = v;
    }
}

// ---------------------------------------------------------------------------
// 3) Suppression bitmask, upper triangle only: row r writes words w >= r>>6.
// ---------------------------------------------------------------------------
__global__ __launch_bounds__(256) void iou_kernel(
    const float4* __restrict__ topBoxes, u64* __restrict__ sup)
{
    int gid = blockIdx.x * 256 + threadIdx.x;
    int wid = gid >> 6;
    int lane = gid & 63;
    int b = wid / TOPN;
    int r = wid - b * TOPN;

    float4 A = topBoxes[(size_t)b * NPAD + r];
    float areaA = (A.z - A.x) * (A.w - A.y);
    size_t supBase = ((size_t)b * NPAD + r) * NW;

    for (int w = r >> 6; w < NW; ++w) {
        int j = w * 64 + lane;
        float4 Bx = topBoxes[(size_t)b * NPAD + j];
        float ix1 = fmaxf(A.x, Bx.x);
        float iy1 = fmaxf(A.y, Bx.y);
        float ix2 = fminf(A.z, Bx.z);
        float iy2 = fminf(A.w, Bx.w);
        float iw = fmaxf(ix2 - ix1, 0.0f);
        float ih = fmaxf(iy2 - iy1, 0.0f);
        float inter = iw * ih;
        float areaB = (Bx.z - Bx.x) * (Bx.w - Bx.y);
        float iou = inter / (areaA + areaB - inter + EPSF);
        bool s = (iou > IOU_T) && (j > r) && (j < TOPN);
        u64 m = __ballot(s);
        if (lane == 0) sup[supBase + w] = m;
    }
}

// ---------------------------------------------------------------------------
// 4) Word-blocked NMS sweep. Double-buffered LDS tiles + 1-ahead register
//    prefetch; lgkm-only barriers. Phase 1's serial chain visits ONLY kept
//    bits whose suppression mask is nonzero (__ballot(m!=0) gate); phase 2
//    gated by rows with any later-word suppression.
// ---------------------------------------------------------------------------
__global__ __launch_bounds__(256) void resolve_kernel(
    const u64* __restrict__ sup, const float4* __restrict__ topBoxes,
    float4* __restrict__ out)
{
    int b = blockIdx.x;
    int tid = threadIdx.x;
    __shared__ u64 tile[2][64 * TSTRIDE];   // 2 x 16.9 KB
    __shared__ u64 keep[NW];
    __shared__ u64 nzmap[NW];               // per word: rows with any sup bits
    __shared__ int wbase[NW];
    if (tid < NW) keep[tid] = (tid < 31) ? ~0ull : 0xFFFFull;  // bits >=2000 off
    const u64* supB = sup + (size_t)b * NPAD * NW;
    unsigned* keep32 = (unsigned*)keep;

    int row = tid >> 2;               // 0..63
    int wcol = (tid & 3) * 8;         // base word within row (8 consecutive)

    // prologue: load + stage tile 0 (rows 0..63, all 32 words; 16 KB)
    {
        const uint4* src = (const uint4*)(supB + tid * 8);
        uint4 p0 = src[0], p1 = src[1], p2 = src[2], p3 = src[3];
        u64* d = &tile[0][row * TSTRIDE + wcol];
        d[0] = ((u64)p0.y << 32) | p0.x;  d[1] = ((u64)p0.w << 32) | p0.z;
        d[2] = ((u64)p1.y << 32) | p1.x;  d[3] = ((u64)p1.w << 32) | p1.z;
        d[4] = ((u64)p2.y << 32) | p2.x;  d[5] = ((u64)p2.w << 32) | p2.z;
        d[6] = ((u64)p3.y << 32) | p3.x;  d[7] = ((u64)p3.w << 32) | p3.z;
    }
    bar_lds();

    for (int w = 0; w < NW; ++w) {
        int buf = w & 1;
        // issue next tile's loads early (stay in flight across both barriers)
        uint4 n0, n1, n2, n3;
        if (w + 1 < NW) {
            const uint4* src = (const uint4*)(supB + (size_t)(w + 1) * 2048 + tid * 8);
            n0 = src[0]; n1 = src[1]; n2 = src[2]; n3 = src[3];
        }

        // phase 1: wave 0 — serial chain over kept SUPPRESSOR bits only.
        if (tid < 64) {
            u64 m = tile[buf][tid * TSTRIDE + w];
            u64 later = 0;
            for (int w2 = w + 1; w2 < NW; ++w2) later |= tile[buf][tid * TSTRIDE + w2];
            u64 nzAny = __ballot((m | later) != 0ull);   // rows needing phase 2
            u64 nzDiag = __ballot(m != 0ull);            // rows acting in-word
            u32 mlo = (u32)m, mhi = (u32)(m >> 32);
            u64 kw64 = keep[w];
            u32 kwlo = (u32)__builtin_amdgcn_readfirstlane((int)(u32)kw64);
            u32 kwhi = (u32)__builtin_amdgcn_readfirstlane((int)(u32)(kw64 >> 32));
            u64 kw = ((u64)kwhi << 32) | kwlo;
            u64 rem = kw & nzDiag;          // kept bits that suppress in-word
            while (rem) {
                int t2 = (int)(__ffsll((unsigned long long)rem) - 1);
                u32 alo = (u32)__builtin_amdgcn_readlane((int)mlo, t2);
                u32 ahi = (u32)__builtin_amdgcn_readlane((int)mhi, t2);
                u64 mt = ((u64)ahi << 32) | alo;   // bits strictly > t2 only
                kw &= ~mt;
                rem &= ~(mt | (1ull << t2));
            }
            if (tid == 0) { keep[w] = kw; nzmap[w] = nzAny; }
        }
        bar_lds();

        // phase 2: apply kept suppressor rows to later words (from LDS)
        u64 gate = keep[w] & nzmap[w];
        int w2 = tid & 31;
        int grp = tid >> 5;              // 8 rows per thread
        if (w2 > w && gate) {
            u64 acc = 0;
#pragma unroll
            for (int q = 0; q < 8; ++q) {
                int rl = grp * 8 + q;
                if ((gate >> rl) & 1ull)
                    acc |= tile[buf][rl * TSTRIDE + w2];
            }
            if (acc) {
                u32 lo = (u32)acc, hi = (u32)(acc >> 32);
                if (lo) atomicAnd(&keep32[2 * w2], ~lo);
                if (hi) atomicAnd(&keep32[2 * w2 + 1], ~hi);
            }
        }

        // stage next tile into the alternate buffer (prev contents consumed)
        if (w + 1 < NW) {
            u64* d = &tile[buf ^ 1][row * TSTRIDE + wcol];
            d[0] = ((u64)n0.y << 32) | n0.x;  d[1] = ((u64)n0.w << 32) | n0.z;
            d[2] = ((u64)n1.y << 32) | n1.x;  d[3] = ((u64)n1.w << 32) | n1.z;
            d[4] = ((u64)n2.y << 32) | n2.x;  d[5] = ((u64)n2.w << 32) | n2.z;
            d[6] = ((u64)n3.y << 32) | n3.x;  d[7] = ((u64)n3.w << 32) | n3.z;
        }
        bar_lds();
    }

    if (tid == 0) {
        int s = 0;
        for (int w2 = 0; w2 < NW; ++w2) { wbase[w2] = s; s += __popcll(keep[w2]); }
    }
    __syncthreads();
    for (int i = tid; i < TOPN; i += 256)
        out[(size_t)b * TOPN + i] = make_float4(0, 0, 0, 0);
    __syncthreads();
    for (int i = tid; i < TOPN; i += 256) {
        int wi = i >> 6, bz = i & 63;
        u64 kw = keep[wi];
        if ((kw >> bz) & 1ull) {
            int pos = wbase[wi] + __popcll(kw & ((1ull << bz) - 1ull));
            out[(size_t)b * TOPN + pos] = topBoxes[(size_t)b * NPAD + i];
        }
    }
}

// ---------------------------------------------------------------------------
// Workspace layout (bytes):
//   sup      : 0           size 8*2048*32*8 = 4,194,304
//   keys     : 4,194,304   size 8*36864*4   = 1,179,648
//   topBoxes : 5,373,952   size 8*2048*16   =   262,144
//   ghist    : 5,636,096   size 8*4096*4    =   131,072  (zeroed each call)
//   total    : 5,767,168 (~5.5 MB)
// ---------------------------------------------------------------------------
extern "C" void kernel_launch(void* const* d_in, const int* in_sizes, int n_in,
                              void* d_out, int out_size, void* d_ws, size_t ws_size,
                              hipStream_t stream)
{
    const float*  scores  = (const float*)d_in[0];
    const float4* offsets = (const float4*)d_in[1];
    const float*  anchors = (const float*)d_in[2];
    float4* out = (float4*)d_out;

    char* ws = (char*)d_ws;
    u64*    sup      = (u64*)(ws);
    u32*    keys     = (u32*)(ws + 4194304);
    float4* topBoxes = (float4*)(ws + 5373952);
    u32*    ghist    = (u32*)(ws + 5636096);

    zero_kernel<<<(131072 / 16 + 255) / 256, 256, 0, stream>>>((uint4*)ghist, 131072 / 16);
    decode_kernel<<<(BATCH * NBOX) / 256, 256, 0, stream>>>(scores, offsets, anchors, keys, ghist);
    select_kernel<<<BATCH, 1024, 0, stream>>>(keys, ghist, scores, offsets, anchors, topBoxes);
    iou_kernel<<<(BATCH * TOPN * 64) / 256, 256, 0, stream>>>(topBoxes, sup);
    resolve_kernel<<<BATCH, 256, 0, stream>>>(sup, topBoxes, out);
}

// Round 14
// 116.034 us; speedup vs baseline: 1.9947x; 1.9947x over previous
//
#include <hip/hip_runtime.h>
#include <stdint.h>

// Match numpy op-for-op rounding: no FMA contraction anywhere.
#pragma clang fp contract(off)

#define BATCH 8
#define HH 64
#define WW 64
#define KA 9
#define NBOX (HH * WW * KA)   // 36864 per batch
#define TOPN 2000
#define NPAD 2048
#define NW 32                 // 64-bit words covering 2048 bits
#define IOU_T 0.7f
#define MINSZ 0.01f
#define EPSF 1e-7f
#define TSTRIDE 33            // LDS tile row stride in u64 (bank-conflict-free)
#define CANDCAP 3072          // candidate buffer (expected ~2300 for uniform)

typedef unsigned int u32;
typedef unsigned long long u64;

__device__ __forceinline__ float clamp01(float x) { return fminf(fmaxf(x, 0.0f), 1.0f); }

// Workgroup barrier with LDS-only drain: does NOT wait vmcnt, so global
// prefetch loads stay in flight across the barrier.
__device__ __forceinline__ void bar_lds()
{
    asm volatile("s_waitcnt lgkmcnt(0)" ::: "memory");
    __builtin_amdgcn_s_barrier();
}

// ---------------------------------------------------------------------------
// Shared box decode (bit-exact same arithmetic everywhere; contract off).
// ---------------------------------------------------------------------------
__device__ __forceinline__ void decode_one(
    const float* __restrict__ scores, const float4* __restrict__ offsets,
    const float* __restrict__ anchors, int gid, int t,
    float4* boxOut, u32* keyOut)
{
    int k = t % KA;
    int pos = t / KA;
    int wx = pos & (WW - 1);
    int hy = pos >> 6;
    float s = scores[gid];
    float4 off = offsets[gid];
    float aw = anchors[2 * k], ah = anchors[2 * k + 1];
    float cx = ((float)wx + 0.5f) * 16.0f;
    float cy = ((float)hy + 0.5f) * 16.0f;
    float pw = (expf(off.z) * aw) / 1024.0f;   // exp(off)*anc/img_wh
    float ph = (expf(off.w) * ah) / 1024.0f;
    float xc = (aw * off.x + cx) / 1024.0f;    // (anc*off + center)/img_wh
    float yc = (ah * off.y + cy) / 1024.0f;
    float x1 = clamp01(xc - pw * 0.5f);
    float y1 = clamp01(yc - ph * 0.5f);
    float x2 = clamp01(xc + pw * 0.5f);
    float y2 = clamp01(yc + ph * 0.5f);
    float sc = clamp01(s);
    float m = ((x2 - x1) > MINSZ && (y2 - y1) > MINSZ) ? 1.0f : 0.0f;
    *boxOut = make_float4(x1 * m, y1 * m, x2 * m, y2 * m);
    *keyOut = __float_as_uint(sc * m);   // score >= 0: bit order == value order
}

// ---------------------------------------------------------------------------
// 0) Zero the global 12-bit histograms (8 x 4096 bins).
// ---------------------------------------------------------------------------
__global__ __launch_bounds__(256) void zero_kernel(uint4* __restrict__ p, int n)
{
    int g = blockIdx.x * 256 + threadIdx.x;
    if (g < n) p[g] = make_uint4(0, 0, 0, 0);
}

// ---------------------------------------------------------------------------
// 1) Decode score keys + per-block LDS histogram, merged to global with ONE
//    atomic per nonzero bin per block (~30/block): skew-tolerant (LDS atomics
//    absorb the hot uniform-score bins; global hot-bin contention <= 144).
// ---------------------------------------------------------------------------
__global__ __launch_bounds__(256) void decode_kernel(
    const float* __restrict__ scores, const float4* __restrict__ offsets,
    const float* __restrict__ anchors, u32* __restrict__ keys,
    u32* __restrict__ ghist)
{
    __shared__ u32 lhist[4096];
    for (int i = threadIdx.x; i < 4096; i += 256) lhist[i] = 0;
    __syncthreads();

    int gid = blockIdx.x * 256 + threadIdx.x;   // grid exactly covers 8*NBOX
    int b = gid / NBOX;                         // uniform per block (256|NBOX)
    int t = gid - b * NBOX;
    float4 box; u32 key;
    decode_one(scores, offsets, anchors, gid, t, &box, &key);
    keys[gid] = key;
    atomicAdd(&lhist[key >> 20], 1u);
    __syncthreads();

    for (int i = threadIdx.x; i < 4096; i += 256) {
        u32 v = lhist[i];
        if (v) atomicAdd(&ghist[(b << 12) + i], v);
    }
}

// ---------------------------------------------------------------------------
// Wave-level descending rank-find over a 4096-bin LDS hist: 2 barriers.
// partial[1024] is scratch. Finds bin P (desc cum crosses r) + residual R.
// ---------------------------------------------------------------------------
__device__ __forceinline__ void rank_find_4096(
    const u32* __restrict__ histL, u32* __restrict__ partial,
    int r, u32* Bsh, int* Rsh, int tid)
{
    partial[tid] = histL[4 * tid] + histL[4 * tid + 1]
                 + histL[4 * tid + 2] + histL[4 * tid + 3];
    __syncthreads();
    if (tid < 64) {
        int lane = tid;
        // superseg l (64 bins) total = partial[16l .. 16l+15]
        u32 s = 0;
#pragma unroll
        for (int q = 0; q < 16; ++q) s += partial[lane * 16 + q];
        u32 suf = s;
#pragma unroll
        for (int d = 1; d < 64; d <<= 1) {
            u32 t = __shfl_down(suf, d);
            if (lane + d < 64) suf += t;
        }
        u32 nxt = __shfl_down(suf, 1);
        if (lane == 63) nxt = 0;
        bool cross = (suf >= (u32)r) && (nxt < (u32)r);   // exactly one lane
        u64 bal = __ballot(cross);
        int L = (int)(__ffsll((unsigned long long)bal) - 1);
        u32 above = __shfl(nxt, L);       // count strictly above superseg L
        // bin level within superseg L
        u32 hv = histL[64 * L + lane];
        u32 suf2 = hv;
#pragma unroll
        for (int d = 1; d < 64; d <<= 1) {
            u32 t = __shfl_down(suf2, d);
            if (lane + d < 64) suf2 += t;
        }
        u32 nxt2 = __shfl_down(suf2, 1);
        if (lane == 63) nxt2 = 0;
        u32 mine2 = suf2 + above;
        nxt2 += above;
        if (mine2 >= (u32)r && nxt2 < (u32)r) {
            *Bsh = (u32)(64 * L + lane);
            *Rsh = r - (int)nxt2;
        }
    }
    __syncthreads();
}

// ---------------------------------------------------------------------------
// 2) Per-batch select, ONE global key stream:
//    global hist (from decode) -> P1/r1; uint4 stream splits definite -> sel
//    and candidates -> cand; 3x12-bit LDS radix over cand -> exact T48;
//    append exactly r1; bitonic sort 2048 desc; re-decode top-2000 boxes.
// ---------------------------------------------------------------------------
__global__ __launch_bounds__(1024) void select_kernel(
    const u32* __restrict__ keys, const u32* __restrict__ ghist,
    const float* __restrict__ scores, const float4* __restrict__ offsets,
    const float* __restrict__ anchors, float4* __restrict__ topBoxes)
{
    int b = blockIdx.x;
    int tid = threadIdx.x;
    int lane = tid & 63;
    const u32* kb = keys + (size_t)b * NBOX;

    __shared__ u32 hist[4096];    // 16 KB
    __shared__ u32 partial[1024]; //  4 KB
    __shared__ u64 sel[NPAD];     // 16 KB
    __shared__ u64 cand[CANDCAP]; // 24 KB  (total ~60.5 KB)
    __shared__ u32 Bsh;
    __shared__ int Rsh;
    __shared__ int ctr, cctr;

    // ---- load global hist; find P1/r1 ----
    if (tid == 0) { ctr = 0; cctr = 0; }
    for (int i = tid; i < 4096; i += 1024) hist[i] = ghist[(b << 12) + i];
    for (int i = tid; i < NPAD; i += 1024) sel[i] = 0ull;
    __syncthreads();
    rank_find_4096(hist, partial, TOPN, &Bsh, &Rsh, tid);
    u32 P1 = Bsh;
    int r1 = Rsh;          // need top-r1 of the candidates (top12 == P1)
    __syncthreads();

    // ---- single uint4 stream: definite -> sel, candidates -> cand ----
    const uint4* kb4 = (const uint4*)kb;
#pragma unroll 1
    for (int it = 0; it < NBOX / 4096; ++it) {
        int i4 = it * 1024 + tid;           // uint4 index
        uint4 kv = kb4[i4];
        u32 karr[4] = { kv.x, kv.y, kv.z, kv.w };
        u64 bd[4], bc[4];
        int totd = 0, totc = 0;
#pragma unroll
        for (int q = 0; q < 4; ++q) {
            u32 top = karr[q] >> 20;
            bd[q] = __ballot(top > P1);
            bc[q] = __ballot(top == P1);
            totd += (int)__popcll(bd[q]);
            totc += (int)__popcll(bc[q]);
        }
        int based = 0, basec = 0;
        if (lane == 0) {
            if (totd) based = atomicAdd(&ctr, totd);
            if (totc) basec = atomicAdd(&cctr, totc);
        }
        based = __shfl(based, 0);
        basec = __shfl(basec, 0);
        u64 lmask = (1ull << lane) - 1ull;
        int offd = 0, offc = 0;
#pragma unroll
        for (int q = 0; q < 4; ++q) {
            u32 key = karr[q];
            int i = i4 * 4 + q;
            u64 K = ((u64)key << 16) | (u64)(0xFFFFu - (u32)i);
            u32 top = key >> 20;
            if (top > P1) {
                int slot = based + offd + (int)__popcll(bd[q] & lmask);
                if (slot < NPAD) sel[slot] = K;
            } else if (top == P1) {
                int cslot = basec + offc + (int)__popcll(bc[q] & lmask);
                if (cslot < CANDCAP) cand[cslot] = K;
            }
            offd += (int)__popcll(bd[q]);
            offc += (int)__popcll(bc[q]);
        }
    }
    __syncthreads();
    int cc = cctr < CANDCAP ? cctr : CANDCAP;

    // ---- 3x12-bit LDS radix over candidates: exact T48 ----
    u64 prefix = (u64)P1;               // == K>>36 for every candidate
    int r = r1;
    for (int p = 0; p < 3; ++p) {
        int shift = 24 - 12 * p;
        for (int i = tid; i < 4096; i += 1024) hist[i] = 0;
        __syncthreads();
        for (int c = tid; c < cc; c += 1024) {
            u64 K = cand[c];
            if ((K >> (shift + 12)) == prefix)
                atomicAdd(&hist[(u32)((K >> shift) & 0xFFFull)], 1u);
        }
        __syncthreads();
        rank_find_4096(hist, partial, r, &Bsh, &Rsh, tid);
        prefix = (prefix << 12) | (u64)Bsh;
        r = Rsh;
        __syncthreads();
    }
    u64 T48 = prefix;   // exact r1-th largest candidate key (unique keys)

    // append exactly r1 candidates >= T48
    for (int c = tid; c < cc; c += 1024) {
        u64 K = cand[c];
        bool take = (K >= T48);
        u64 bal = __ballot(take);
        int base = 0;
        if (lane == 0 && bal) base = atomicAdd(&ctr, (int)__popcll(bal));
        base = __shfl(base, 0);
        if (take) {
            int slot = base + (int)__popcll(bal & ((1ull << lane) - 1ull));
            if (slot < NPAD) sel[slot] = K;
        }
    }
    __syncthreads();

    // ---- bitonic sort 2048 desc ----
    for (int k = 2; k <= NPAD; k <<= 1) {
        for (int j = k >> 1; j > 0; j >>= 1) {
#pragma unroll
            for (int n = 0; n < 2; ++n) {
                int i = tid + n * 1024;
                int ixj = i ^ j;
                if (ixj > i) {
                    bool desc = ((i & k) == 0);
                    u64 a = sel[i], c = sel[ixj];
                    if (desc ? (a < c) : (a > c)) { sel[i] = c; sel[ixj] = a; }
                }
            }
            __syncthreads();
        }
    }

    // re-decode top-2000 boxes; rows 2000..2047 zeroed for safe loads
    for (int i = tid; i < NPAD; i += 1024) {
        float4 v = make_float4(0, 0, 0, 0);
        if (i < TOPN) {
            u64 K = sel[i];
            int idx = 0xFFFF - (int)(K & 0xFFFFull);
            u32 kdummy;
            decode_one(scores, offsets, anchors, b * NBOX + idx, idx, &v, &kdummy);
        }
        topBoxes[b * NPAD + i] = v;
    }
}

// ---------------------------------------------------------------------------
// 3) Suppression bitmask, upper triangle only: row r writes words w >= r>>6.
// ---------------------------------------------------------------------------
__global__ __launch_bounds__(256) void iou_kernel(
    const float4* __restrict__ topBoxes, u64* __restrict__ sup)
{
    int gid = blockIdx.x * 256 + threadIdx.x;
    int wid = gid >> 6;
    int lane = gid & 63;
    int b = wid / TOPN;
    int r = wid - b * TOPN;

    float4 A = topBoxes[(size_t)b * NPAD + r];
    float areaA = (A.z - A.x) * (A.w - A.y);
    size_t supBase = ((size_t)b * NPAD + r) * NW;

    for (int w = r >> 6; w < NW; ++w) {
        int j = w * 64 + lane;
        float4 Bx = topBoxes[(size_t)b * NPAD + j];
        float ix1 = fmaxf(A.x, Bx.x);
        float iy1 = fmaxf(A.y, Bx.y);
        float ix2 = fminf(A.z, Bx.z);
        float iy2 = fminf(A.w, Bx.w);
        float iw = fmaxf(ix2 - ix1, 0.0f);
        float ih = fmaxf(iy2 - iy1, 0.0f);
        float inter = iw * ih;
        float areaB = (Bx.z - Bx.x) * (Bx.w - Bx.y);
        float iou = inter / (areaA + areaB - inter + EPSF);
        bool s = (iou > IOU_T) && (j > r) && (j < TOPN);
        u64 m = __ballot(s);
        if (lane == 0) sup[supBase + w] = m;
    }
}

// ---------------------------------------------------------------------------
// 4) Word-blocked NMS sweep. Double-buffered LDS tiles + 1-ahead register
//    prefetch; lgkm-only barriers. Phase 1's serial chain visits ONLY kept
//    bits whose suppression mask is nonzero (__ballot(m!=0) gate); phase 2
//    gated by rows with any later-word suppression.
// ---------------------------------------------------------------------------
__global__ __launch_bounds__(256) void resolve_kernel(
    const u64* __restrict__ sup, const float4* __restrict__ topBoxes,
    float4* __restrict__ out)
{
    int b = blockIdx.x;
    int tid = threadIdx.x;
    __shared__ u64 tile[2][64 * TSTRIDE];   // 2 x 16.9 KB
    __shared__ u64 keep[NW];
    __shared__ u64 nzmap[NW];               // per word: rows with any sup bits
    __shared__ int wbase[NW];
    if (tid < NW) keep[tid] = (tid < 31) ? ~0ull : 0xFFFFull;  // bits >=2000 off
    const u64* supB = sup + (size_t)b * NPAD * NW;
    unsigned* keep32 = (unsigned*)keep;

    int row = tid >> 2;               // 0..63
    int wcol = (tid & 3) * 8;         // base word within row (8 consecutive)

    // prologue: load + stage tile 0 (rows 0..63, all 32 words; 16 KB)
    {
        const uint4* src = (const uint4*)(supB + tid * 8);
        uint4 p0 = src[0], p1 = src[1], p2 = src[2], p3 = src[3];
        u64* d = &tile[0][row * TSTRIDE + wcol];
        d[0] = ((u64)p0.y << 32) | p0.x;  d[1] = ((u64)p0.w << 32) | p0.z;
        d[2] = ((u64)p1.y << 32) | p1.x;  d[3] = ((u64)p1.w << 32) | p1.z;
        d[4] = ((u64)p2.y << 32) | p2.x;  d[5] = ((u64)p2.w << 32) | p2.z;
        d[6] = ((u64)p3.y << 32) | p3.x;  d[7] = ((u64)p3.w << 32) | p3.z;
    }
    bar_lds();

    for (int w = 0; w < NW; ++w) {
        int buf = w & 1;
        // issue next tile's loads early (stay in flight across both barriers)
        uint4 n0, n1, n2, n3;
        if (w + 1 < NW) {
            const uint4* src = (const uint4*)(supB + (size_t)(w + 1) * 2048 + tid * 8);
            n0 = src[0]; n1 = src[1]; n2 = src[2]; n3 = src[3];
        }

        // phase 1: wave 0 — serial chain over kept SUPPRESSOR bits only.
        if (tid < 64) {
            u64 m = tile[buf][tid * TSTRIDE + w];
            u64 later = 0;
            for (int w2 = w + 1; w2 < NW; ++w2) later |= tile[buf][tid * TSTRIDE + w2];
            u64 nzAny = __ballot((m | later) != 0ull);   // rows needing phase 2
            u64 nzDiag = __ballot(m != 0ull);            // rows acting in-word
            u32 mlo = (u32)m, mhi = (u32)(m >> 32);
            u64 kw64 = keep[w];
            u32 kwlo = (u32)__builtin_amdgcn_readfirstlane((int)(u32)kw64);
            u32 kwhi = (u32)__builtin_amdgcn_readfirstlane((int)(u32)(kw64 >> 32));
            u64 kw = ((u64)kwhi << 32) | kwlo;
            u64 rem = kw & nzDiag;          // kept bits that suppress in-word
            while (rem) {
                int t2 = (int)(__ffsll((unsigned long long)rem) - 1);
                u32 alo = (u32)__builtin_amdgcn_readlane((int)mlo, t2);
                u32 ahi = (u32)__builtin_amdgcn_readlane((int)mhi, t2);
                u64 mt = ((u64)ahi << 32) | alo;   // bits strictly > t2 only
                kw &= ~mt;
                rem &= ~(mt | (1ull << t2));
            }
            if (tid == 0) { keep[w] = kw; nzmap[w] = nzAny; }
        }
        bar_lds();

        // phase 2: apply kept suppressor rows to later words (from LDS)
        u64 gate = keep[w] & nzmap[w];
        int w2 = tid & 31;
        int grp = tid >> 5;              // 8 rows per thread
        if (w2 > w && gate) {
            u64 acc = 0;
#pragma unroll
            for (int q = 0; q < 8; ++q) {
                int rl = grp * 8 + q;
                if ((gate >> rl) & 1ull)
                    acc |= tile[buf][rl * TSTRIDE + w2];
            }
            if (acc) {
                u32 lo = (u32)acc, hi = (u32)(acc >> 32);
                if (lo) atomicAnd(&keep32[2 * w2], ~lo);
                if (hi) atomicAnd(&keep32[2 * w2 + 1], ~hi);
            }
        }

        // stage next tile into the alternate buffer (prev contents consumed)
        if (w + 1 < NW) {
            u64* d = &tile[buf ^ 1][row * TSTRIDE + wcol];
            d[0] = ((u64)n0.y << 32) | n0.x;  d[1] = ((u64)n0.w << 32) | n0.z;
            d[2] = ((u64)n1.y << 32) | n1.x;  d[3] = ((u64)n1.w << 32) | n1.z;
            d[4] = ((u64)n2.y << 32) | n2.x;  d[5] = ((u64)n2.w << 32) | n2.z;
            d[6] = ((u64)n3.y << 32) | n3.x;  d[7] = ((u64)n3.w << 32) | n3.z;
        }
        bar_lds();
    }

    if (tid == 0) {
        int s = 0;
        for (int w2 = 0; w2 < NW; ++w2) { wbase[w2] = s; s += __popcll(keep[w2]); }
    }
    __syncthreads();
    for (int i = tid; i < TOPN; i += 256)
        out[(size_t)b * TOPN + i] = make_float4(0, 0, 0, 0);
    __syncthreads();
    for (int i = tid; i < TOPN; i += 256) {
        int wi = i >> 6, bz = i & 63;
        u64 kw = keep[wi];
        if ((kw >> bz) & 1ull) {
            int pos = wbase[wi] + __popcll(kw & ((1ull << bz) - 1ull));
            out[(size_t)b * TOPN + pos] = topBoxes[(size_t)b * NPAD + i];
        }
    }
}

// ---------------------------------------------------------------------------
// Workspace layout (bytes):
//   sup      : 0           size 8*2048*32*8 = 4,194,304
//   keys     : 4,194,304   size 8*36864*4   = 1,179,648
//   topBoxes : 5,373,952   size 8*2048*16   =   262,144
//   ghist    : 5,636,096   size 8*4096*4    =   131,072  (zeroed each call)
//   total    : 5,767,168 (~5.5 MB)
// ---------------------------------------------------------------------------
extern "C" void kernel_launch(void* const* d_in, const int* in_sizes, int n_in,
                              void* d_out, int out_size, void* d_ws, size_t ws_size,
                              hipStream_t stream)
{
    const float*  scores  = (const float*)d_in[0];
    const float4* offsets = (const float4*)d_in[1];
    const float*  anchors = (const float*)d_in[2];
    float4* out = (float4*)d_out;

    char* ws = (char*)d_ws;
    u64*    sup      = (u64*)(ws);
    u32*    keys     = (u32*)(ws + 4194304);
    float4* topBoxes = (float4*)(ws + 5373952);
    u32*    ghist    = (u32*)(ws + 5636096);

    zero_kernel<<<(131072 / 16 + 255) / 256, 256, 0, stream>>>((uint4*)ghist, 131072 / 16);
    decode_kernel<<<(BATCH * NBOX) / 256, 256, 0, stream>>>(scores, offsets, anchors, keys, ghist);
    select_kernel<<<BATCH, 1024, 0, stream>>>(keys, ghist, scores, offsets, anchors, topBoxes);
    iou_kernel<<<(BATCH * TOPN * 64) / 256, 256, 0, stream>>>(topBoxes, sup);
    resolve_kernel<<<BATCH, 256, 0, stream>>>(sup, topBoxes, out);
}

// Round 15
// 106.437 us; speedup vs baseline: 2.1746x; 1.0902x over previous
//
#include <hip/hip_runtime.h>
#include <stdint.h>

// Match numpy op-for-op rounding: no FMA contraction anywhere.
#pragma clang fp contract(off)

#define BATCH 8
#define HH 64
#define WW 64
#define KA 9
#define NBOX (HH * WW * KA)   // 36864 per batch
#define TOPN 2000
#define NPAD 2048
#define NW 32                 // 64-bit words covering 2048 bits
#define IOU_T 0.7f
#define MINSZ 0.01f
#define EPSF 1e-7f
#define TSTRIDE 33            // LDS tile row stride in u64 (bank-conflict-free)
#define CANDCAP 3072          // candidate buffer (expected ~2300 for uniform)

typedef unsigned int u32;
typedef unsigned long long u64;

__device__ __forceinline__ float clamp01(float x) { return fminf(fmaxf(x, 0.0f), 1.0f); }

// Workgroup barrier with LDS-only drain: does NOT wait vmcnt, so global
// prefetch loads stay in flight across the barrier.
__device__ __forceinline__ void bar_lds()
{
    asm volatile("s_waitcnt lgkmcnt(0)" ::: "memory");
    __builtin_amdgcn_s_barrier();
}

// ---------------------------------------------------------------------------
// Shared box decode (bit-exact same arithmetic everywhere; contract off).
// ---------------------------------------------------------------------------
__device__ __forceinline__ void decode_one(
    const float* __restrict__ scores, const float4* __restrict__ offsets,
    const float* __restrict__ anchors, int gid, int t,
    float4* boxOut, u32* keyOut)
{
    int k = t % KA;
    int pos = t / KA;
    int wx = pos & (WW - 1);
    int hy = pos >> 6;
    float s = scores[gid];
    float4 off = offsets[gid];
    float aw = anchors[2 * k], ah = anchors[2 * k + 1];
    float cx = ((float)wx + 0.5f) * 16.0f;
    float cy = ((float)hy + 0.5f) * 16.0f;
    float pw = (expf(off.z) * aw) / 1024.0f;   // exp(off)*anc/img_wh
    float ph = (expf(off.w) * ah) / 1024.0f;
    float xc = (aw * off.x + cx) / 1024.0f;    // (anc*off + center)/img_wh
    float yc = (ah * off.y + cy) / 1024.0f;
    float x1 = clamp01(xc - pw * 0.5f);
    float y1 = clamp01(yc - ph * 0.5f);
    float x2 = clamp01(xc + pw * 0.5f);
    float y2 = clamp01(yc + ph * 0.5f);
    float sc = clamp01(s);
    float m = ((x2 - x1) > MINSZ && (y2 - y1) > MINSZ) ? 1.0f : 0.0f;
    *boxOut = make_float4(x1 * m, y1 * m, x2 * m, y2 * m);
    *keyOut = __float_as_uint(sc * m);   // score >= 0: bit order == value order
}

// ---------------------------------------------------------------------------
// 0) Zero the global 12-bit histograms (8 x 4096 bins).
// ---------------------------------------------------------------------------
__global__ __launch_bounds__(256) void zero_kernel(uint4* __restrict__ p, int n)
{
    int g = blockIdx.x * 256 + threadIdx.x;
    if (g < n) p[g] = make_uint4(0, 0, 0, 0);
}

// ---------------------------------------------------------------------------
// 1) Decode score keys + per-block LDS histogram, merged to global with ONE
//    atomic per nonzero bin per block (skew-tolerant).
// ---------------------------------------------------------------------------
__global__ __launch_bounds__(256) void decode_kernel(
    const float* __restrict__ scores, const float4* __restrict__ offsets,
    const float* __restrict__ anchors, u32* __restrict__ keys,
    u32* __restrict__ ghist)
{
    __shared__ u32 lhist[4096];
    for (int i = threadIdx.x; i < 4096; i += 256) lhist[i] = 0;
    __syncthreads();

    int gid = blockIdx.x * 256 + threadIdx.x;   // grid exactly covers 8*NBOX
    int b = gid / NBOX;                         // uniform per block (256|NBOX)
    int t = gid - b * NBOX;
    float4 box; u32 key;
    decode_one(scores, offsets, anchors, gid, t, &box, &key);
    keys[gid] = key;
    atomicAdd(&lhist[key >> 20], 1u);
    __syncthreads();

    for (int i = threadIdx.x; i < 4096; i += 256) {
        u32 v = lhist[i];
        if (v) atomicAdd(&ghist[(b << 12) + i], v);
    }
}

// ---------------------------------------------------------------------------
// Wave-level descending rank-find over a 4096-bin LDS hist: 2 barriers.
// ---------------------------------------------------------------------------
__device__ __forceinline__ void rank_find_4096(
    const u32* __restrict__ histL, u32* __restrict__ partial,
    int r, u32* Bsh, int* Rsh, int tid)
{
    partial[tid] = histL[4 * tid] + histL[4 * tid + 1]
                 + histL[4 * tid + 2] + histL[4 * tid + 3];
    __syncthreads();
    if (tid < 64) {
        int lane = tid;
        u32 s = 0;
#pragma unroll
        for (int q = 0; q < 16; ++q) s += partial[lane * 16 + q];
        u32 suf = s;
#pragma unroll
        for (int d = 1; d < 64; d <<= 1) {
            u32 t = __shfl_down(suf, d);
            if (lane + d < 64) suf += t;
        }
        u32 nxt = __shfl_down(suf, 1);
        if (lane == 63) nxt = 0;
        bool cross = (suf >= (u32)r) && (nxt < (u32)r);   // exactly one lane
        u64 bal = __ballot(cross);
        int L = (int)(__ffsll((unsigned long long)bal) - 1);
        u32 above = __shfl(nxt, L);       // count strictly above superseg L
        u32 hv = histL[64 * L + lane];
        u32 suf2 = hv;
#pragma unroll
        for (int d = 1; d < 64; d <<= 1) {
            u32 t = __shfl_down(suf2, d);
            if (lane + d < 64) suf2 += t;
        }
        u32 nxt2 = __shfl_down(suf2, 1);
        if (lane == 63) nxt2 = 0;
        u32 mine2 = suf2 + above;
        nxt2 += above;
        if (mine2 >= (u32)r && nxt2 < (u32)r) {
            *Bsh = (u32)(64 * L + lane);
            *Rsh = r - (int)nxt2;
        }
    }
    __syncthreads();
}

// ---------------------------------------------------------------------------
// 2) Per-batch select, ONE global key stream + in-register bitonic sort:
//    thread t holds elements t and t+1024 (lane-major), so all stages with
//    j<=32 are same-wave __shfl_xor (no barrier, no LDS); j=1024 is
//    in-thread; only j in {64..512} use LDS (14 stages x 2 barriers = 28
//    barriers vs 66). Epilogue decodes top-2000 boxes from registers.
// ---------------------------------------------------------------------------
__global__ __launch_bounds__(1024) void select_kernel(
    const u32* __restrict__ keys, const u32* __restrict__ ghist,
    const float* __restrict__ scores, const float4* __restrict__ offsets,
    const float* __restrict__ anchors, float4* __restrict__ topBoxes)
{
    int b = blockIdx.x;
    int tid = threadIdx.x;
    int lane = tid & 63;
    const u32* kb = keys + (size_t)b * NBOX;

    __shared__ u32 hist[4096];    // 16 KB
    __shared__ u32 partial[1024]; //  4 KB
    __shared__ u64 sel[NPAD];     // 16 KB
    __shared__ u64 cand[CANDCAP]; // 24 KB  (total ~60.5 KB)
    __shared__ u32 Bsh;
    __shared__ int Rsh;
    __shared__ int ctr, cctr;

    // ---- load global hist; find P1/r1 ----
    if (tid == 0) { ctr = 0; cctr = 0; }
    for (int i = tid; i < 4096; i += 1024) hist[i] = ghist[(b << 12) + i];
    for (int i = tid; i < NPAD; i += 1024) sel[i] = 0ull;
    __syncthreads();
    rank_find_4096(hist, partial, TOPN, &Bsh, &Rsh, tid);
    u32 P1 = Bsh;
    int r1 = Rsh;          // need top-r1 of the candidates (top12 == P1)
    __syncthreads();

    // ---- single uint4 stream: definite -> sel, candidates -> cand ----
    const uint4* kb4 = (const uint4*)kb;
#pragma unroll 1
    for (int it = 0; it < NBOX / 4096; ++it) {
        int i4 = it * 1024 + tid;           // uint4 index
        uint4 kv = kb4[i4];
        u32 karr[4] = { kv.x, kv.y, kv.z, kv.w };
        u64 bd[4], bc[4];
        int totd = 0, totc = 0;
#pragma unroll
        for (int q = 0; q < 4; ++q) {
            u32 top = karr[q] >> 20;
            bd[q] = __ballot(top > P1);
            bc[q] = __ballot(top == P1);
            totd += (int)__popcll(bd[q]);
            totc += (int)__popcll(bc[q]);
        }
        int based = 0, basec = 0;
        if (lane == 0) {
            if (totd) based = atomicAdd(&ctr, totd);
            if (totc) basec = atomicAdd(&cctr, totc);
        }
        based = __shfl(based, 0);
        basec = __shfl(basec, 0);
        u64 lmask = (1ull << lane) - 1ull;
        int offd = 0, offc = 0;
#pragma unroll
        for (int q = 0; q < 4; ++q) {
            u32 key = karr[q];
            int i = i4 * 4 + q;
            u64 K = ((u64)key << 16) | (u64)(0xFFFFu - (u32)i);
            u32 top = key >> 20;
            if (top > P1) {
                int slot = based + offd + (int)__popcll(bd[q] & lmask);
                if (slot < NPAD) sel[slot] = K;
            } else if (top == P1) {
                int cslot = basec + offc + (int)__popcll(bc[q] & lmask);
                if (cslot < CANDCAP) cand[cslot] = K;
            }
            offd += (int)__popcll(bd[q]);
            offc += (int)__popcll(bc[q]);
        }
    }
    __syncthreads();
    int cc = cctr < CANDCAP ? cctr : CANDCAP;

    // ---- 3x12-bit LDS radix over candidates: exact T48 ----
    u64 prefix = (u64)P1;               // == K>>36 for every candidate
    int r = r1;
    for (int p = 0; p < 3; ++p) {
        int shift = 24 - 12 * p;
        for (int i = tid; i < 4096; i += 1024) hist[i] = 0;
        __syncthreads();
        for (int c = tid; c < cc; c += 1024) {
            u64 K = cand[c];
            if ((K >> (shift + 12)) == prefix)
                atomicAdd(&hist[(u32)((K >> shift) & 0xFFFull)], 1u);
        }
        __syncthreads();
        rank_find_4096(hist, partial, r, &Bsh, &Rsh, tid);
        prefix = (prefix << 12) | (u64)Bsh;
        r = Rsh;
        __syncthreads();
    }
    u64 T48 = prefix;   // exact r1-th largest candidate key (unique keys)

    // append exactly r1 candidates >= T48
    for (int c = tid; c < cc; c += 1024) {
        u64 K = cand[c];
        bool take = (K >= T48);
        u64 bal = __ballot(take);
        int base = 0;
        if (lane == 0 && bal) base = atomicAdd(&ctr, (int)__popcll(bal));
        base = __shfl(base, 0);
        if (take) {
            int slot = base + (int)__popcll(bal & ((1ull << lane) - 1ull));
            if (slot < NPAD) sel[slot] = K;
        }
    }
    __syncthreads();

    // ---- bitonic sort 2048 desc, register-resident ----
    // element i0 = tid (lane-major within wave), i1 = tid + 1024.
    u64 e0 = sel[tid];
    u64 e1 = sel[tid + 1024];
    const int i0 = tid, i1 = tid + 1024;

    for (int k = 2; k <= NPAD; k <<= 1) {
        // stages with j >= 64: LDS exchange (j == 1024 is in-thread)
        for (int j = k >> 1; j >= 64; j >>= 1) {
            if (j == 1024) {
                // partner of i0 is i1; k == 2048 -> (i0 & k) == 0 -> descending
                u64 mx = e0 > e1 ? e0 : e1;
                u64 mn = e0 > e1 ? e1 : e0;
                e0 = mx; e1 = mn;
            } else {
                sel[i0] = e0; sel[i1] = e1;
                __syncthreads();
                u64 p0 = sel[i0 ^ j];
                u64 p1 = sel[i1 ^ j];
                bool kp0 = ((i0 & k) == 0) ^ ((i0 & j) != 0);
                bool kp1 = ((i1 & k) == 0) ^ ((i1 & j) != 0);
                e0 = kp0 ? (e0 > p0 ? e0 : p0) : (e0 < p0 ? e0 : p0);
                e1 = kp1 ? (e1 > p1 ? e1 : p1) : (e1 < p1 ? e1 : p1);
                __syncthreads();
            }
        }
        // stages with j <= 32: same-wave shuffle exchange (no barriers)
        int jstart = (k >> 1) < 32 ? (k >> 1) : 32;
        for (int j = jstart; j >= 1; j >>= 1) {
            u64 p0 = __shfl_xor(e0, j);
            u64 p1 = __shfl_xor(e1, j);
            bool kp0 = ((i0 & k) == 0) ^ ((i0 & j) != 0);
            bool kp1 = ((i1 & k) == 0) ^ ((i1 & j) != 0);
            e0 = kp0 ? (e0 > p0 ? e0 : p0) : (e0 < p0 ? e0 : p0);
            e1 = kp1 ? (e1 > p1 ? e1 : p1) : (e1 < p1 ? e1 : p1);
        }
    }

    // ---- epilogue: decode top-2000 boxes straight from registers ----
    // e0 holds rank i0 = tid (< 1024 < TOPN: always decode)
    {
        float4 v; u32 kd;
        int idx = 0xFFFF - (int)(e0 & 0xFFFFull);
        decode_one(scores, offsets, anchors, b * NBOX + idx, idx, &v, &kd);
        topBoxes[b * NPAD + i0] = v;
    }
    // e1 holds rank i1 = tid + 1024 (decode if < TOPN, else zero row)
    {
        float4 v = make_float4(0, 0, 0, 0);
        if (i1 < TOPN) {
            u32 kd;
            int idx = 0xFFFF - (int)(e1 & 0xFFFFull);
            decode_one(scores, offsets, anchors, b * NBOX + idx, idx, &v, &kd);
        }
        topBoxes[b * NPAD + i1] = v;
    }
}

// ---------------------------------------------------------------------------
// 3) Suppression bitmask, upper triangle only: row r writes words w >= r>>6.
// ---------------------------------------------------------------------------
__global__ __launch_bounds__(256) void iou_kernel(
    const float4* __restrict__ topBoxes, u64* __restrict__ sup)
{
    int gid = blockIdx.x * 256 + threadIdx.x;
    int wid = gid >> 6;
    int lane = gid & 63;
    int b = wid / TOPN;
    int r = wid - b * TOPN;

    float4 A = topBoxes[(size_t)b * NPAD + r];
    float areaA = (A.z - A.x) * (A.w - A.y);
    size_t supBase = ((size_t)b * NPAD + r) * NW;

    for (int w = r >> 6; w < NW; ++w) {
        int j = w * 64 + lane;
        float4 Bx = topBoxes[(size_t)b * NPAD + j];
        float ix1 = fmaxf(A.x, Bx.x);
        float iy1 = fmaxf(A.y, Bx.y);
        float ix2 = fminf(A.z, Bx.z);
        float iy2 = fminf(A.w, Bx.w);
        float iw = fmaxf(ix2 - ix1, 0.0f);
        float ih = fmaxf(iy2 - iy1, 0.0f);
        float inter = iw * ih;
        float areaB = (Bx.z - Bx.x) * (Bx.w - Bx.y);
        float iou = inter / (areaA + areaB - inter + EPSF);
        bool s = (iou > IOU_T) && (j > r) && (j < TOPN);
        u64 m = __ballot(s);
        if (lane == 0) sup[supBase + w] = m;
    }
}

// ---------------------------------------------------------------------------
// 4) Word-blocked NMS sweep. Double-buffered LDS tiles + 1-ahead register
//    prefetch; lgkm-only barriers. Phase 1's serial chain visits ONLY kept
//    bits whose suppression mask is nonzero; phase 2 gated likewise.
// ---------------------------------------------------------------------------
__global__ __launch_bounds__(256) void resolve_kernel(
    const u64* __restrict__ sup, const float4* __restrict__ topBoxes,
    float4* __restrict__ out)
{
    int b = blockIdx.x;
    int tid = threadIdx.x;
    __shared__ u64 tile[2][64 * TSTRIDE];   // 2 x 16.9 KB
    __shared__ u64 keep[NW];
    __shared__ u64 nzmap[NW];               // per word: rows with any sup bits
    __shared__ int wbase[NW];
    if (tid < NW) keep[tid] = (tid < 31) ? ~0ull : 0xFFFFull;  // bits >=2000 off
    const u64* supB = sup + (size_t)b * NPAD * NW;
    unsigned* keep32 = (unsigned*)keep;

    int row = tid >> 2;               // 0..63
    int wcol = (tid & 3) * 8;         // base word within row (8 consecutive)

    // prologue: load + stage tile 0 (rows 0..63, all 32 words; 16 KB)
    {
        const uint4* src = (const uint4*)(supB + tid * 8);
        uint4 p0 = src[0], p1 = src[1], p2 = src[2], p3 = src[3];
        u64* d = &tile[0][row * TSTRIDE + wcol];
        d[0] = ((u64)p0.y << 32) | p0.x;  d[1] = ((u64)p0.w << 32) | p0.z;
        d[2] = ((u64)p1.y << 32) | p1.x;  d[3] = ((u64)p1.w << 32) | p1.z;
        d[4] = ((u64)p2.y << 32) | p2.x;  d[5] = ((u64)p2.w << 32) | p2.z;
        d[6] = ((u64)p3.y << 32) | p3.x;  d[7] = ((u64)p3.w << 32) | p3.z;
    }
    bar_lds();

    for (int w = 0; w < NW; ++w) {
        int buf = w & 1;
        // issue next tile's loads early (stay in flight across both barriers)
        uint4 n0, n1, n2, n3;
        if (w + 1 < NW) {
            const uint4* src = (const uint4*)(supB + (size_t)(w + 1) * 2048 + tid * 8);
            n0 = src[0]; n1 = src[1]; n2 = src[2]; n3 = src[3];
        }

        // phase 1: wave 0 — serial chain over kept SUPPRESSOR bits only.
        if (tid < 64) {
            u64 m = tile[buf][tid * TSTRIDE + w];
            u64 later = 0;
            for (int w2 = w + 1; w2 < NW; ++w2) later |= tile[buf][tid * TSTRIDE + w2];
            u64 nzAny = __ballot((m | later) != 0ull);   // rows needing phase 2
            u64 nzDiag = __ballot(m != 0ull);            // rows acting in-word
            u32 mlo = (u32)m, mhi = (u32)(m >> 32);
            u64 kw64 = keep[w];
            u32 kwlo = (u32)__builtin_amdgcn_readfirstlane((int)(u32)kw64);
            u32 kwhi = (u32)__builtin_amdgcn_readfirstlane((int)(u32)(kw64 >> 32));
            u64 kw = ((u64)kwhi << 32) | kwlo;
            u64 rem = kw & nzDiag;          // kept bits that suppress in-word
            while (rem) {
                int t2 = (int)(__ffsll((unsigned long long)rem) - 1);
                u32 alo = (u32)__builtin_amdgcn_readlane((int)mlo, t2);
                u32 ahi = (u32)__builtin_amdgcn_readlane((int)mhi, t2);
                u64 mt = ((u64)ahi << 32) | alo;   // bits strictly > t2 only
                kw &= ~mt;
                rem &= ~(mt | (1ull << t2));
            }
            if (tid == 0) { keep[w] = kw; nzmap[w] = nzAny; }
        }
        bar_lds();

        // phase 2: apply kept suppressor rows to later words (from LDS)
        u64 gate = keep[w] & nzmap[w];
        int w2 = tid & 31;
        int grp = tid >> 5;              // 8 rows per thread
        if (w2 > w && gate) {
            u64 acc = 0;
#pragma unroll
            for (int q = 0; q < 8; ++q) {
                int rl = grp * 8 + q;
                if ((gate >> rl) & 1ull)
                    acc |= tile[buf][rl * TSTRIDE + w2];
            }
            if (acc) {
                u32 lo = (u32)acc, hi = (u32)(acc >> 32);
                if (lo) atomicAnd(&keep32[2 * w2], ~lo);
                if (hi) atomicAnd(&keep32[2 * w2 + 1], ~hi);
            }
        }

        // stage next tile into the alternate buffer (prev contents consumed)
        if (w + 1 < NW) {
            u64* d = &tile[buf ^ 1][row * TSTRIDE + wcol];
            d[0] = ((u64)n0.y << 32) | n0.x;  d[1] = ((u64)n0.w << 32) | n0.z;
            d[2] = ((u64)n1.y << 32) | n1.x;  d[3] = ((u64)n1.w << 32) | n1.z;
            d[4] = ((u64)n2.y << 32) | n2.x;  d[5] = ((u64)n2.w << 32) | n2.z;
            d[6] = ((u64)n3.y << 32) | n3.x;  d[7] = ((u64)n3.w << 32) | n3.z;
        }
        bar_lds();
    }

    if (tid == 0) {
        int s = 0;
        for (int w2 = 0; w2 < NW; ++w2) { wbase[w2] = s; s += __popcll(keep[w2]); }
    }
    __syncthreads();
    for (int i = tid; i < TOPN; i += 256)
        out[(size_t)b * TOPN + i] = make_float4(0, 0, 0, 0);
    __syncthreads();
    for (int i = tid; i < TOPN; i += 256) {
        int wi = i >> 6, bz = i & 63;
        u64 kw = keep[wi];
        if ((kw >> bz) & 1ull) {
            int pos = wbase[wi] + __popcll(kw & ((1ull << bz) - 1ull));
            out[(size_t)b * TOPN + pos] = topBoxes[(size_t)b * NPAD + i];
        }
    }
}

// ---------------------------------------------------------------------------
// Workspace layout (bytes):
//   sup      : 0           size 8*2048*32*8 = 4,194,304
//   keys     : 4,194,304   size 8*36864*4   = 1,179,648
//   topBoxes : 5,373,952   size 8*2048*16   =   262,144
//   ghist    : 5,636,096   size 8*4096*4    =   131,072  (zeroed each call)
//   total    : 5,767,168 (~5.5 MB)
// ---------------------------------------------------------------------------
extern "C" void kernel_launch(void* const* d_in, const int* in_sizes, int n_in,
                              void* d_out, int out_size, void* d_ws, size_t ws_size,
                              hipStream_t stream)
{
    const float*  scores  = (const float*)d_in[0];
    const float4* offsets = (const float4*)d_in[1];
    const float*  anchors = (const float*)d_in[2];
    float4* out = (float4*)d_out;

    char* ws = (char*)d_ws;
    u64*    sup      = (u64*)(ws);
    u32*    keys     = (u32*)(ws + 4194304);
    float4* topBoxes = (float4*)(ws + 5373952);
    u32*    ghist    = (u32*)(ws + 5636096);

    zero_kernel<<<(131072 / 16 + 255) / 256, 256, 0, stream>>>((uint4*)ghist, 131072 / 16);
    decode_kernel<<<(BATCH * NBOX) / 256, 256, 0, stream>>>(scores, offsets, anchors, keys, ghist);
    select_kernel<<<BATCH, 1024, 0, stream>>>(keys, ghist, scores, offsets, anchors, topBoxes);
    iou_kernel<<<(BATCH * TOPN * 64) / 256, 256, 0, stream>>>(topBoxes, sup);
    resolve_kernel<<<BATCH, 256, 0, stream>>>(sup, topBoxes, out);
}